// Round 17
// baseline (349.857 us; speedup 1.0000x reference)
//
#include <hip/hip_runtime.h>
#include <hip/hip_bf16.h>

typedef __attribute__((ext_vector_type(8))) short bf16x8;
typedef __attribute__((ext_vector_type(4))) float f32x4;

#define BATCH 8
#define LEN 4096
#define DIN 1024
#define DST 512
#define KHALF 256
#define DOUT 1024
#define NCHUNK 64
#define CHUNK 64

static __device__ __forceinline__ ushort f2bf(float f) {
    uint x = __float_as_uint(f);
    uint r = (x + 0x7fffu + ((x >> 16) & 1u)) >> 16;
    return (ushort)r;
}
static __device__ __forceinline__ float bf2f(ushort u) {
    return __uint_as_float((uint)u << 16);
}

// async global->LDS, 16B per lane; LDS dest = wave-uniform base + lane*16
#define GL16(gp, lp) __builtin_amdgcn_global_load_lds( \
    (const __attribute__((address_space(1))) void*)(gp), \
    (__attribute__((address_space(3))) void*)(lp), 16, 0, 0)

// ---------------- rmsnorm: u (32768 x 1024) f32 -> un bf16 ----------------
__global__ __launch_bounds__(256)
void rmsnorm_kernel(const float* __restrict__ u, const float* __restrict__ w,
                    ushort* __restrict__ un)
{
    const int row = blockIdx.x;
    const int t = threadIdx.x;
    const float4 v = ((const float4*)(u + (size_t)row * DIN))[t];
    float ss = v.x*v.x + v.y*v.y + v.z*v.z + v.w*v.w;
    #pragma unroll
    for (int m = 32; m >= 1; m >>= 1) ss += __shfl_xor(ss, m, 64);
    __shared__ float partial[4];
    if ((t & 63) == 0) partial[t >> 6] = ss;
    __syncthreads();
    const float total = partial[0] + partial[1] + partial[2] + partial[3];
    const float scale = rsqrtf(total * (1.0f / DIN) + 1e-6f);
    const float4 wv = ((const float4*)w)[t];
    ushort4 o;
    o.x = f2bf(v.x * scale * wv.x);
    o.y = f2bf(v.y * scale * wv.y);
    o.z = f2bf(v.z * scale * wv.z);
    o.w = f2bf(v.w * scale * wv.w);
    ((ushort4*)(un + (size_t)row * DIN))[t] = o;
}

// ---------------- transpose + cast to bf16 ----------------
__global__ __launch_bounds__(256)
void transpose_bf16_kernel(const float* __restrict__ src, ushort* __restrict__ dst,
                           int R, int C)
{
    const int id = blockIdx.x * 256 + threadIdx.x;
    if (id >= R * C) return;
    const int r = id / C, c = id % C;
    dst[(size_t)c * R + r] = f2bf(src[id]);
}

// ---------------- bf16 MFMA GEMM, 2-phase double-buffered (T3 minimum form) ----
// 128x128 tile, BK=64, 4 waves (2x2), global_load_lds staging with pre-swizzled
// source (rule #21). One __syncthreads per K-step: barrier drains stage(cur)
// [vmcnt(0)] AND prev iter's ds_reads [lgkmcnt]; stage(next) issued after the
// barrier overwrites only the buffer whose reads completed in the PREVIOUS
// iteration (protected by this barrier). XCD-banded 1D block swizzle.
#define BM 128
#define BN 128
#define BK 64
__global__ __launch_bounds__(256, 3)
void gemm_bt_kernel(const ushort* __restrict__ A, const ushort* __restrict__ Bt,
                    void* __restrict__ Cout, int M, int N, int K, int Nt, int obf)
{
    __shared__ ushort sA[2][BM * BK];
    __shared__ ushort sB[2][BN * BK];
    const int tid = threadIdx.x;
    const int lane = tid & 63;
    const int wave = tid >> 6;
    const int wr = wave >> 1, wc = wave & 1;

    const int b = blockIdx.x;
    const int slot = b >> 3;
    const int mt = (b & 7) + 8 * (slot / Nt);
    const int nt = slot - (slot / Nt) * Nt;
    const int m0 = mt * BM, n0 = nt * BN;

    const size_t K2 = (size_t)K * 2;          // bytes per row
    const int srow = tid >> 3;                // 0..31
    const int scol = ((tid & 7) << 4) ^ ((srow & 7) << 4);
    const char* gA = (const char*)A + (size_t)(m0 + srow) * K2 + scol;
    const char* gB = (const char*)Bt + (size_t)(n0 + srow) * K2 + scol;
    const int ldsBase = wave * 1024;          // + c2*4096; HW adds lane*16

    f32x4 acc[4][4] = {};

    const int nkt = K / BK;
    // prologue: stage K-tile 0 into buffer 0
    {
        const size_t kOff = 0;
        #pragma unroll
        for (int c2 = 0; c2 < 4; ++c2) {
            GL16(gA + (size_t)c2 * 32 * K2 + kOff, (char*)sA[0] + ldsBase + c2 * 4096);
            GL16(gB + (size_t)c2 * 32 * K2 + kOff, (char*)sB[0] + ldsBase + c2 * 4096);
        }
    }
    for (int kt = 0; kt < nkt; ++kt) {
        const int cur = kt & 1;
        __syncthreads();   // vmcnt(0): stage(cur) landed; lgkm: prev reads done
        if (kt + 1 < nkt) {
            const size_t kOff = (size_t)(kt + 1) * (BK * 2);
            #pragma unroll
            for (int c2 = 0; c2 < 4; ++c2) {
                GL16(gA + (size_t)c2 * 32 * K2 + kOff, (char*)sA[cur ^ 1] + ldsBase + c2 * 4096);
                GL16(gB + (size_t)c2 * 32 * K2 + kOff, (char*)sB[cur ^ 1] + ldsBase + c2 * 4096);
            }
        }
        #pragma unroll
        for (int kk = 0; kk < 2; ++kk) {
            bf16x8 af[4], bfr[4];
            #pragma unroll
            for (int i = 0; i < 4; ++i) {
                const int arow = wr * 64 + i * 16 + (lane & 15);
                const int aoff = arow * 128 + ((kk * 64 + (lane >> 4) * 16) ^ ((arow & 7) << 4));
                af[i] = *(const bf16x8*)((const char*)sA[cur] + aoff);
                const int brow = wc * 64 + i * 16 + (lane & 15);
                const int boff = brow * 128 + ((kk * 64 + (lane >> 4) * 16) ^ ((brow & 7) << 4));
                bfr[i] = *(const bf16x8*)((const char*)sB[cur] + boff);
            }
            #pragma unroll
            for (int i = 0; i < 4; ++i)
                #pragma unroll
                for (int j = 0; j < 4; ++j)
                    acc[i][j] = __builtin_amdgcn_mfma_f32_16x16x32_bf16(af[i], bfr[j], acc[i][j], 0, 0, 0);
        }
    }
    // epilogue: C[(lane>>4)*4 + r][lane&15] per frag (m89-verified layout)
    if (obf) {
        ushort* base = (ushort*)Cout;
        #pragma unroll
        for (int i = 0; i < 4; ++i) {
            #pragma unroll
            for (int j = 0; j < 4; ++j) {
                const int row = m0 + wr * 64 + i * 16 + (lane >> 4) * 4;
                const int col = n0 + wc * 64 + j * 16 + (lane & 15);
                ushort* cp = base + (size_t)row * N + col;
                #pragma unroll
                for (int r = 0; r < 4; ++r)
                    cp[(size_t)r * N] = f2bf(acc[i][j][r]);
            }
        }
    } else {
        float* base = (float*)Cout;
        #pragma unroll
        for (int i = 0; i < 4; ++i) {
            #pragma unroll
            for (int j = 0; j < 4; ++j) {
                const int row = m0 + wr * 64 + i * 16 + (lane >> 4) * 4;
                const int col = n0 + wc * 64 + j * 16 + (lane & 15);
                float* cp = base + (size_t)row * N + col;
                #pragma unroll
                for (int r = 0; r < 4; ++r)
                    cp[(size_t)r * N] = acc[i][j][r];
            }
        }
    }
}

// ---------------- scan phase A: per-chunk local finals (zero carry-in) ----------------
// uB is bf16-packed [b][l][k][2]
__global__ __launch_bounds__(256)
void scan_local_kernel(const ushort* __restrict__ uB, const float* __restrict__ A,
                       float* __restrict__ L)
{
    const int c = blockIdx.x, b = blockIdx.y, k = threadIdx.x;
    const float a00 = A[4*k+0], a01 = A[4*k+1], a10 = A[4*k+2], a11 = A[4*k+3];
    const ushort2* p = (const ushort2*)uB + ((size_t)b * LEN + c * CHUNK) * KHALF + k;
    float s0 = 0.f, s1 = 0.f;
    #pragma unroll 8
    for (int j = 0; j < CHUNK; ++j) {
        const ushort2 uv = p[(size_t)j * KHALF];
        const float ux = bf2f(uv.x), uy = bf2f(uv.y);
        const float t0 = fmaf(s0, a00, fmaf(s1, a10, ux));
        const float t1 = fmaf(s0, a01, fmaf(s1, a11, uy));
        s0 = t0; s1 = t1;
    }
    ((float2*)L)[((size_t)b * NCHUNK + c) * KHALF + k] = make_float2(s0, s1);
}

// ---------------- scan phase C: final pass (carry recomputed in-block from L) ----
// carry-in for chunk c = c applications of (s = A^64 s + L[j]) starting at x0 —
// identical operation order to the old scan_carry kernel (bit-exact).
__global__ __launch_bounds__(256)
void scan_final_kernel(const ushort* __restrict__ uB, const float* __restrict__ A,
                       const float* __restrict__ L, const float* __restrict__ x0,
                       ushort* __restrict__ xbf, float* __restrict__ state_out)
{
    const int c = blockIdx.x, b = blockIdx.y, k = threadIdx.x;
    const float a00 = A[4*k+0], a01 = A[4*k+1], a10 = A[4*k+2], a11 = A[4*k+3];
    // A^64 by 6 squarings (same as old scan_carry)
    float m00 = a00, m01 = a01, m10 = a10, m11 = a11;
    #pragma unroll
    for (int i = 0; i < 6; ++i) {
        const float n00 = m00*m00 + m01*m10;
        const float n01 = m00*m01 + m01*m11;
        const float n10 = m10*m00 + m11*m10;
        const float n11 = m10*m01 + m11*m11;
        m00 = n00; m01 = n01; m10 = n10; m11 = n11;
    }
    float s0 = x0[((size_t)b * KHALF + k) * 2 + 0];
    float s1 = x0[((size_t)b * KHALF + k) * 2 + 1];
    for (int j = 0; j < c; ++j) {
        const float2 Lj = ((const float2*)L)[((size_t)b * NCHUNK + j) * KHALF + k];
        const float t0 = s0 * m00 + s1 * m10 + Lj.x;
        const float t1 = s0 * m01 + s1 * m11 + Lj.y;
        s0 = t0; s1 = t1;
    }
    const ushort2* p = (const ushort2*)uB + ((size_t)b * LEN + c * CHUNK) * KHALF + k;
    uint* xp = (uint*)xbf + ((size_t)b * LEN + c * CHUNK) * KHALF + k;
    #pragma unroll 8
    for (int j = 0; j < CHUNK; ++j) {
        const ushort2 uv = p[(size_t)j * KHALF];
        const float ux = bf2f(uv.x), uy = bf2f(uv.y);
        const float t0 = fmaf(s0, a00, fmaf(s1, a10, ux));
        const float t1 = fmaf(s0, a01, fmaf(s1, a11, uy));
        s0 = t0; s1 = t1;
        xp[(size_t)j * KHALF] = (uint)f2bf(s0) | ((uint)f2bf(s1) << 16);
    }
    if (c == NCHUNK - 1) {
        ((float2*)state_out)[(size_t)b * KHALF + k] = make_float2(s0, s1);
    }
}

extern "C" void kernel_launch(void* const* d_in, const int* in_sizes, int n_in,
                              void* d_out, int out_size, void* d_ws, size_t ws_size,
                              hipStream_t stream)
{
    (void)in_sizes; (void)n_in; (void)out_size; (void)ws_size;
    const float* u  = (const float*)d_in[0];
    const float* x0 = (const float*)d_in[1];
    const float* A  = (const float*)d_in[2];
    const float* B  = (const float*)d_in[3];
    const float* C  = (const float*)d_in[4];
    const float* w  = (const float*)d_in[5];
    float* y_out = (float*)d_out;
    float* state_out = y_out + (size_t)BATCH * LEN * DOUT;

    char* ws = (char*)d_ws;
    ushort* un    = (ushort*)(ws + 0);           // 64 MB
    ushort* Bt    = (ushort*)(ws + 67108864);    //  1 MB
    ushort* Ct    = (ushort*)(ws + 68157440);    //  1 MB
    ushort* uBbf  = (ushort*)(ws + 69206016);    // 32 MB (bf16)
    ushort* xbf   = (ushort*)(ws + 136314880);   // 32 MB
    float*  L     = (float*)(ws + 169869312);    //  1 MB

    transpose_bf16_kernel<<<dim3((DIN * DST + 255) / 256), 256, 0, stream>>>(B, Bt, DIN, DST);
    transpose_bf16_kernel<<<dim3((DST * DOUT + 255) / 256), 256, 0, stream>>>(C, Ct, DST, DOUT);
    rmsnorm_kernel<<<dim3(BATCH * LEN), 256, 0, stream>>>(u, w, un);
    // GEMM1: 32768x512x1024, Mt=256, Nt=4 -> 1024 blocks; bf16 output
    gemm_bt_kernel<<<dim3(256 * 4), 256, 0, stream>>>(un, Bt, (void*)uBbf, BATCH * LEN, DST, DIN, 4, 1);
    scan_local_kernel<<<dim3(NCHUNK, BATCH), 256, 0, stream>>>(uBbf, A, L);
    scan_final_kernel<<<dim3(NCHUNK, BATCH), 256, 0, stream>>>(uBbf, A, L, x0, xbf, state_out);
    // GEMM2: 32768x1024x512, Mt=256, Nt=8 -> 2048 blocks; f32 output
    gemm_bt_kernel<<<dim3(256 * 8), 256, 0, stream>>>(xbf, Ct, (void*)y_out, BATCH * LEN, DOUT, DST, 8, 0);
}